// Round 9
// baseline (41.654 us; speedup 1.0000x reference)
//
#include <hip/hip_runtime.h>
#include <hip/hip_bf16.h>

#define Bsz 16
#define Nn  128
#define NFd 64
#define NDd 100
#define NHd 64

typedef __attribute__((ext_vector_type(8))) short bf16x8;
typedef __attribute__((ext_vector_type(4))) float f32x4;

__device__ __forceinline__ short f2bf(float f) {
  return (short)__builtin_bit_cast(ushort, __float2bfloat16(f));
}

__device__ __forceinline__ float fast_tanh(float x) {
  // tanh(x) = 1 - 2/(exp(2x)+1); exact at +/-inf, ~1ulp rcp error (<< bf16 noise)
  float e = __expf(2.0f * x);
  return 1.0f - 2.0f * __builtin_amdgcn_rcpf(e + 1.0f);
}

// async global->LDS DMA: LDS dest = uniform base + lane*size; global src per-lane
__device__ __forceinline__ void glds16(const float* g, float* l) {
  __builtin_amdgcn_global_load_lds(
      (const __attribute__((address_space(1))) void*)g,
      (__attribute__((address_space(3))) void*)l, 16, 0, 0);
}
__device__ __forceinline__ void glds4(const float* g, float* l) {
  __builtin_amdgcn_global_load_lds(
      (const __attribute__((address_space(1))) void*)g,
      (__attribute__((address_space(3))) void*)l, 4, 0, 0);
}

// ---------------- prep kernel ----------------
// blocks [0,512):   atomhT[b,h,j] = b_cf[h] + sum_f AF[b,j,f]*W_cf[f,h]  (TRANSPOSED)
//                   + out init: out[b,j,:] = AF[b,j,:]
// blocks [512,544): pack W_df -> bf16 MFMA-B fragments, K zero-padded to 128
// blocks [544,560): pack W_fc -> bf16 MFMA-B fragments (K=64)
__global__ __launch_bounds__(256) void prep_kernel(
    const float* __restrict__ AF, const float* __restrict__ Wcf,
    const float* __restrict__ bcf, const float* __restrict__ Wdf,
    const float* __restrict__ Wfc, float* __restrict__ atomhT,
    ushort* __restrict__ wdfp, ushort* __restrict__ wfcp,
    float* __restrict__ out) {
  int t = threadIdx.x;
  int blk = blockIdx.x;
  if (blk < 512) {
    int row = blk * 4 + (t >> 6);        // b*N + j
    int h = t & 63;
    const float* af = AF + (size_t)row * NFd;
    float a0 = 0.f, a1 = 0.f, a2 = 0.f, a3 = 0.f;
    #pragma unroll 4
    for (int f = 0; f < NFd; f += 4) {
      a0 += af[f + 0] * Wcf[(f + 0) * NHd + h];
      a1 += af[f + 1] * Wcf[(f + 1) * NHd + h];
      a2 += af[f + 2] * Wcf[(f + 2) * NHd + h];
      a3 += af[f + 3] * Wcf[(f + 3) * NHd + h];
    }
    int b = row >> 7, j = row & 127;
    atomhT[((size_t)(b * NHd + h)) << 7 | j] = bcf[h] + ((a0 + a1) + (a2 + a3));
    out[(size_t)row * NFd + h] = af[h];  // out pre-init = atom_features
  } else if (blk < 544) {
    // wdfp[(grp*64 + col)*8 + e] = bf16(Wdf[k = grp*8+e][col]), 0 if k >= 100
    int idx = (blk - 512) * 256 + t;     // [0, 8192)
    int e = idx & 7;
    int col = (idx >> 3) & 63;
    int grp = idx >> 9;
    int k = grp * 8 + e;
    float v = (k < NDd) ? Wdf[k * NHd + col] : 0.f;
    wdfp[idx] = (ushort)f2bf(v);
  } else {
    int idx = (blk - 544) * 256 + t;     // [0, 4096)
    int e = idx & 7;
    int col = (idx >> 3) & 63;
    int grp = idx >> 9;
    int k = grp * 8 + e;
    wfcp[idx] = (ushort)f2bf(Wfc[k * NFd + col]);
  }
}

// ---------------- main kernel: one block per (bi,half), 4 independent waves ----------------
// Wave w owns 16 j-rows. DM staged K-MAJOR, block-XOR-swizzled:
//   LDS word(c,r,b_lds,d) = c*512 + r*32 + b_lds*4 + d  holds  dm[r][32c + 4*(b_lds^(r&7)) + d]
// Row tails (k=96..100) at words 1536..1599 as [r][4] (no aliasing). Gate operands
// (atomhT) + mask + bias preloaded BEFORE the single vmcnt(0) drain. Gated bf16 tile
// reuses chunk-0 words (wave-ordered). No __syncthreads; atomic partial-add epilogue.
__global__ __launch_bounds__(256, 4) void dtnn_main_kernel(
    const float* __restrict__ DM,
    const float* __restrict__ MASK,
    const float* __restrict__ bdf,
    const float* __restrict__ atomhT,
    const ushort* __restrict__ wdfp,
    const ushort* __restrict__ wfcp,
    float* __restrict__ out) {
  __shared__ float stage[4 * 1600];      // 25.6 KB, wave-private 1600-f32 slabs

  const int t    = threadIdx.x;
  const int blk  = blockIdx.x;           // [0, 4096)
  const int bi   = blk >> 1;             // b*N + i
  const int half = blk & 1;
  const int b    = bi >> 7;
  const int w    = t >> 6;               // wave 0..3
  const int lane = t & 63;
  const int p    = t & 15;
  const int q    = (t >> 4) & 3;

  const int jrow = half * 64 + w * 16;   // this wave's global j base

  // ---- issue 7 GLDS ops: 3 k-chunks x 2 row-groups (swizzled) + row-tail gather ----
  const float* gsrc = DM + (size_t)bi * (Nn * NDd) + (size_t)jrow * NDd;
  float* lb = stage + w * 1600;
  {
    const int r8 = lane >> 3, b8 = lane & 7;
    #pragma unroll
    for (int c = 0; c < 3; ++c) {
      #pragma unroll
      for (int g = 0; g < 2; ++g) {
        int r = g * 8 + r8;
        glds16(gsrc + r * 100 + c * 32 + ((b8 ^ (r & 7)) << 2),
               lb + c * 512 + g * 256);
      }
    }
    glds4(gsrc + (lane >> 2) * 100 + 96 + (lane & 3), lb + 1536);
  }

  const bf16x8* wdfv = reinterpret_cast<const bf16x8*>(wdfp);
  const bf16x8* wfcv = reinterpret_cast<const bf16x8*>(wfcp);

  // ---- preload gate/mask/bias operands (independent of staged data) ----
  f32x4 ah[4];
  #pragma unroll
  for (int ht = 0; ht < 4; ++ht)
    ah[ht] = *reinterpret_cast<const f32x4*>(
        atomhT + (((size_t)(b * NHd + ht * 16 + p)) << 7) + jrow + 4 * q);
  f32x4 mv = *reinterpret_cast<const f32x4*>(MASK + (size_t)bi * Nn + jrow + 4 * q);
  float bv[4];
  #pragma unroll
  for (int ht = 0; ht < 4; ++ht) bv[ht] = bdf[ht * 16 + p];

  asm volatile("s_waitcnt vmcnt(0)" ::: "memory");
  __builtin_amdgcn_sched_barrier(0);

  // ---- phase 1: dist_h[j,h] = dm[j,:].W_df[:,h] + b_df[h], K=100 ----
  f32x4 acc[4];
  #pragma unroll
  for (int ht = 0; ht < 4; ++ht) acc[ht] = (f32x4){bv[ht], bv[ht], bv[ht], bv[ht]};

  #pragma unroll
  for (int ks = 0; ks < 3; ++ks) {       // k = [0,96), conflict-free swizzled reads
    const float* cbase = lb + ks * 512 + p * 32;
    f32x4 x = *reinterpret_cast<const f32x4*>(cbase + (((2 * q)     ) ^ (p & 7)) * 4);
    f32x4 y = *reinterpret_cast<const f32x4*>(cbase + (((2 * q) + 1 ) ^ (p & 7)) * 4);
    bf16x8 a;
    a[0] = f2bf(x[0]); a[1] = f2bf(x[1]); a[2] = f2bf(x[2]); a[3] = f2bf(x[3]);
    a[4] = f2bf(y[0]); a[5] = f2bf(y[1]); a[6] = f2bf(y[2]); a[7] = f2bf(y[3]);
    #pragma unroll
    for (int ht = 0; ht < 4; ++ht)
      acc[ht] = __builtin_amdgcn_mfma_f32_16x16x32_bf16(
          a, wdfv[(ks * 4 + q) * 64 + ht * 16 + p], acc[ht], 0, 0, 0);
  }
  {                                      // tail k = [96,100): only q==0 carries data
    bf16x8 a = (bf16x8){0, 0, 0, 0, 0, 0, 0, 0};
    if (q == 0) {
      f32x4 tx = *reinterpret_cast<const f32x4*>(lb + 1536 + 4 * p);
      a[0] = f2bf(tx[0]); a[1] = f2bf(tx[1]); a[2] = f2bf(tx[2]); a[3] = f2bf(tx[3]);
    }
    #pragma unroll
    for (int ht = 0; ht < 4; ++ht)
      acc[ht] = __builtin_amdgcn_mfma_f32_16x16x32_bf16(
          a, wdfv[(12 + q) * 64 + ht * 16 + p], acc[ht], 0, 0, 0);
  }

  // ---- gate: acc[j][h] *= atomh[b,j,h]  (D: row j=jrow+4q+r, col h=16ht+p) ----
  #pragma unroll
  for (int ht = 0; ht < 4; ++ht) {
    #pragma unroll
    for (int r = 0; r < 4; ++r) acc[ht][r] *= ah[ht][r];
  }

  // ---- write gated (bf16, XOR-swizzled [16][64]) over chunk-0 words ----
  ushort* gb = reinterpret_cast<ushort*>(lb);
  #pragma unroll
  for (int r = 0; r < 4; ++r) {
    int rr = 4 * q + r;                  // local row 0..15
    int sw = (rr & 7) << 3;
    #pragma unroll
    for (int ht = 0; ht < 4; ++ht)
      gb[rr * 64 + ((ht * 16 + p) ^ sw)] = (ushort)f2bf(acc[ht][r]);
  }
  asm volatile("" ::: "memory");         // keep phase-2 reads below the writes

  // ---- phase 2: pre[j,f] = gated[j,:].W_fc[:,f], K=64 ----
  f32x4 acc2[4];
  #pragma unroll
  for (int ft = 0; ft < 4; ++ft) acc2[ft] = (f32x4){0.f, 0.f, 0.f, 0.f};

  #pragma unroll
  for (int ks = 0; ks < 2; ++ks) {
    int h0 = (ks * 32 + q * 8) ^ ((p & 7) << 3);
    bf16x8 a2 = *reinterpret_cast<const bf16x8*>(&gb[p * 64 + h0]);
    #pragma unroll
    for (int ft = 0; ft < 4; ++ft)
      acc2[ft] = __builtin_amdgcn_mfma_f32_16x16x32_bf16(
          a2, wfcv[(ks * 4 + q) * 64 + ft * 16 + p], acc2[ft], 0, 0, 0);
  }

  // ---- mask, tanh, accumulate this wave's 16 rows ----
  float s[4] = {0.f, 0.f, 0.f, 0.f};
  #pragma unroll
  for (int r = 0; r < 4; ++r) {
    #pragma unroll
    for (int ft = 0; ft < 4; ++ft) s[ft] += fast_tanh(acc2[ft][r] * mv[r]);
  }

  // ---- reduce over q in-wave, then atomic partial-add to out ----
  #pragma unroll
  for (int ft = 0; ft < 4; ++ft) {
    s[ft] += __shfl_xor(s[ft], 16, 64);
    s[ft] += __shfl_xor(s[ft], 32, 64);
  }
  if (q == 0) {
    #pragma unroll
    for (int ft = 0; ft < 4; ++ft)
      unsafeAtomicAdd(&out[(size_t)bi * NFd + ft * 16 + p], s[ft]);
  }
}

extern "C" void kernel_launch(void* const* d_in, const int* in_sizes, int n_in,
                              void* d_out, int out_size, void* d_ws, size_t ws_size,
                              hipStream_t stream) {
  const float* AF   = (const float*)d_in[0];
  const float* DM   = (const float*)d_in[1];
  const float* MASK = (const float*)d_in[2];
  const float* Wcf  = (const float*)d_in[3];
  const float* Wdf  = (const float*)d_in[4];
  const float* Wfc  = (const float*)d_in[5];
  const float* bcf  = (const float*)d_in[6];
  const float* bdf  = (const float*)d_in[7];
  float* out = (float*)d_out;

  float*  atomhT = (float*)d_ws;                                  // 512 KB (transposed [b][h][j])
  ushort* wdfp   = (ushort*)((char*)d_ws + 524288);               // 16 KB (K padded to 128)
  ushort* wfcp   = (ushort*)((char*)d_ws + 524288 + 16384);       // 8 KB

  prep_kernel<<<560, 256, 0, stream>>>(AF, Wcf, bcf, Wdf, Wfc, atomhT, wdfp, wfcp, out);
  dtnn_main_kernel<<<2 * Bsz * Nn, 256, 0, stream>>>(DM, MASK, bdf, atomhT, wdfp, wfcp, out);
}

// Round 10
// 34.010 us; speedup vs baseline: 1.2248x; 1.2248x over previous
//
#include <hip/hip_runtime.h>
#include <hip/hip_bf16.h>

#define Bsz 16
#define Nn  128
#define NFd 64
#define NDd 100
#define NHd 64

typedef __attribute__((ext_vector_type(8))) short bf16x8;
typedef __attribute__((ext_vector_type(4))) float f32x4;

__device__ __forceinline__ short f2bf(float f) {
  return (short)__builtin_bit_cast(ushort, __float2bfloat16(f));
}

__device__ __forceinline__ float fast_tanh(float x) {
  // tanh(x) = 1 - 2/(exp(2x)+1); exact at +/-inf, ~1ulp rcp error (<< bf16 noise)
  float e = __expf(2.0f * x);
  return 1.0f - 2.0f * __builtin_amdgcn_rcpf(e + 1.0f);
}

// async global->LDS DMA: LDS dest = uniform base + lane*size; global src per-lane
__device__ __forceinline__ void glds16(const float* g, float* l) {
  __builtin_amdgcn_global_load_lds(
      (const __attribute__((address_space(1))) void*)g,
      (__attribute__((address_space(3))) void*)l, 16, 0, 0);
}
__device__ __forceinline__ void glds4(const float* g, float* l) {
  __builtin_amdgcn_global_load_lds(
      (const __attribute__((address_space(1))) void*)g,
      (__attribute__((address_space(3))) void*)l, 4, 0, 0);
}

// ---------------- prep kernel ----------------
// blocks [0,512):   atomhT[b,h,j] = b_cf[h] + sum_f AF[b,j,f]*W_cf[f,h]  (transposed)
// blocks [512,544): pack W_df -> bf16 MFMA-B fragments, K zero-padded to 128
// blocks [544,560): pack W_fc -> bf16 MFMA-B fragments (K=64)
__global__ __launch_bounds__(256) void prep_kernel(
    const float* __restrict__ AF, const float* __restrict__ Wcf,
    const float* __restrict__ bcf, const float* __restrict__ Wdf,
    const float* __restrict__ Wfc, float* __restrict__ atomhT,
    ushort* __restrict__ wdfp, ushort* __restrict__ wfcp) {
  int t = threadIdx.x;
  int blk = blockIdx.x;
  if (blk < 512) {
    int row = blk * 4 + (t >> 6);        // b*N + j
    int h = t & 63;
    const float* af = AF + (size_t)row * NFd;
    float a0 = 0.f, a1 = 0.f, a2 = 0.f, a3 = 0.f;
    #pragma unroll 4
    for (int f = 0; f < NFd; f += 4) {
      a0 += af[f + 0] * Wcf[(f + 0) * NHd + h];
      a1 += af[f + 1] * Wcf[(f + 1) * NHd + h];
      a2 += af[f + 2] * Wcf[(f + 2) * NHd + h];
      a3 += af[f + 3] * Wcf[(f + 3) * NHd + h];
    }
    int b = row >> 7, j = row & 127;
    atomhT[((size_t)(b * NHd + h)) << 7 | j] = bcf[h] + ((a0 + a1) + (a2 + a3));
  } else if (blk < 544) {
    // wdfp[(grp*64 + col)*8 + e] = bf16(Wdf[k = grp*8+e][col]), 0 if k >= 100
    int idx = (blk - 512) * 256 + t;     // [0, 8192)
    int e = idx & 7;
    int col = (idx >> 3) & 63;
    int grp = idx >> 9;
    int k = grp * 8 + e;
    float v = (k < NDd) ? Wdf[k * NHd + col] : 0.f;
    wdfp[idx] = (ushort)f2bf(v);
  } else {
    int idx = (blk - 544) * 256 + t;     // [0, 4096)
    int e = idx & 7;
    int col = (idx >> 3) & 63;
    int grp = idx >> 9;
    int k = grp * 8 + e;
    wfcp[idx] = (ushort)f2bf(Wfc[k * NFd + col]);
  }
}

// ---------------- main kernel: 512 persistent blocks, wave w owns bi = 4*blk + w ----------------
// 8 tiles of 16 j-rows per wave, software-pipelined with EXACT vmcnt bookkeeping:
// per tile the ONLY VMEM is 7 GLDS + 4 gate + 1 mask = 12 ops (weights live in LDS,
// read via lgkmcnt; no atomics; out written once per wave). Steady state:
// ISSUE(n+1)[12] -> s_waitcnt vmcnt(12) (retires exactly tile n) -> COMPUTE(n) (LDS-only).
// Every wave keeps 12-24 loads in flight continuously -> smooth HBM stream.
__global__ __launch_bounds__(256, 2) void dtnn_main_kernel(
    const float* __restrict__ AF,
    const float* __restrict__ DM,
    const float* __restrict__ MASK,
    const float* __restrict__ bdf,
    const float* __restrict__ atomhT,
    const ushort* __restrict__ wdfp,
    const ushort* __restrict__ wfcp,
    float* __restrict__ out) {
  __shared__ float  stage[4 * 2 * 1600];   // 51.2 KB: wave w, parity par -> w*3200 + par*1600
  __shared__ ushort wdf_lds[8192];         // 16 KB  phase-1 B fragments
  __shared__ ushort wfc_lds[4096];         // 8 KB   phase-2 B fragments

  const int t    = threadIdx.x;
  const int w    = t >> 6;
  const int lane = t & 63;
  const int p    = t & 15;
  const int q    = (t >> 4) & 3;

  const int bi = blockIdx.x * 4 + w;       // this wave's output row (b*N + i)
  const int b  = bi >> 7;

  // ---- stage weights into LDS (6 GLDS per wave, round-robin), zero VGPR cost ----
  {
    const float* wsrc = (const float*)wdfp;           // 16 KB = 16 x 1KB ops
    float* wdst = reinterpret_cast<float*>(wdf_lds);
    #pragma unroll
    for (int m = 0; m < 4; ++m) {
      int k = w + 4 * m;
      glds16(wsrc + k * 256 + lane * 4, wdst + k * 256);
    }
    const float* fsrc = (const float*)wfcp;           // 8 KB = 8 x 1KB ops
    float* fdst = reinterpret_cast<float*>(wfc_lds);
    #pragma unroll
    for (int m = 0; m < 2; ++m) {
      int k = w + 4 * m;
      glds16(fsrc + k * 256 + lane * 4, fdst + k * 256);
    }
  }

  // bias fragments (tile-invariant) -> registers, before the barrier drain
  float bv[4];
  #pragma unroll
  for (int ht = 0; ht < 4; ++ht) bv[ht] = bdf[ht * 16 + p];

  const float* gD = DM + (size_t)bi * (Nn * NDd);
  f32x4 ah[2][4];                          // gate operands, double-buffered by tile parity
  f32x4 mv[2];
  const int r8 = lane >> 3, b8 = lane & 7;

  // ISSUE(n): exactly 12 VMEM ops (7 GLDS k-major swizzled + 4 gate + 1 mask)
  auto ISSUE = [&](int n) {
    const float* gsrc = gD + n * 1600;
    float* lb = &stage[w * 3200 + (n & 1) * 1600];
    #pragma unroll
    for (int c = 0; c < 3; ++c) {
      #pragma unroll
      for (int g = 0; g < 2; ++g) {
        int r = g * 8 + r8;
        glds16(gsrc + r * 100 + c * 32 + ((b8 ^ (r & 7)) << 2),
               lb + c * 512 + g * 256);
      }
    }
    glds4(gsrc + (lane >> 2) * 100 + 96 + (lane & 3), lb + 1536);
    const int jrow = n * 16;
    #pragma unroll
    for (int ht = 0; ht < 4; ++ht)
      ah[n & 1][ht] = *reinterpret_cast<const f32x4*>(
          atomhT + (((size_t)(b * NHd + ht * 16 + p)) << 7) + jrow + 4 * q);
    mv[n & 1] = *reinterpret_cast<const f32x4*>(MASK + (size_t)bi * Nn + jrow + 4 * q);
  };

  ISSUE(0);
  __syncthreads();                         // weights (and tile 0) resident; once per block

  float s[4] = {0.f, 0.f, 0.f, 0.f};

  #pragma unroll
  for (int n = 0; n < 8; ++n) {
    if (n < 7) {
      ISSUE(n + 1);
      asm volatile("s_waitcnt vmcnt(12)" ::: "memory");  // retires exactly tile n's 12 ops
    } else {
      asm volatile("s_waitcnt vmcnt(0)" ::: "memory");
    }
    __builtin_amdgcn_sched_barrier(0);

    float* lb = &stage[w * 3200 + (n & 1) * 1600];

    // ---- phase 1: dist_h[j,h] = dm[j,:].W_df[:,h] + b_df[h], K=100 ----
    f32x4 acc[4];
    #pragma unroll
    for (int ht = 0; ht < 4; ++ht) acc[ht] = (f32x4){bv[ht], bv[ht], bv[ht], bv[ht]};

    #pragma unroll
    for (int ks = 0; ks < 3; ++ks) {       // k = [0,96), conflict-free swizzled reads
      const float* cbase = lb + ks * 512 + p * 32;
      f32x4 x = *reinterpret_cast<const f32x4*>(cbase + (((2 * q)    ) ^ (p & 7)) * 4);
      f32x4 y = *reinterpret_cast<const f32x4*>(cbase + (((2 * q) + 1) ^ (p & 7)) * 4);
      bf16x8 a;
      a[0] = f2bf(x[0]); a[1] = f2bf(x[1]); a[2] = f2bf(x[2]); a[3] = f2bf(x[3]);
      a[4] = f2bf(y[0]); a[5] = f2bf(y[1]); a[6] = f2bf(y[2]); a[7] = f2bf(y[3]);
      #pragma unroll
      for (int ht = 0; ht < 4; ++ht) {
        bf16x8 bfr = *reinterpret_cast<const bf16x8*>(
            &wdf_lds[((ks * 4 + q) * 64 + ht * 16 + p) * 8]);
        acc[ht] = __builtin_amdgcn_mfma_f32_16x16x32_bf16(a, bfr, acc[ht], 0, 0, 0);
      }
    }
    {                                      // tail k = [96,100): only q==0 carries data
      bf16x8 a = (bf16x8){0, 0, 0, 0, 0, 0, 0, 0};
      if (q == 0) {
        f32x4 tx = *reinterpret_cast<const f32x4*>(lb + 1536 + 4 * p);
        a[0] = f2bf(tx[0]); a[1] = f2bf(tx[1]); a[2] = f2bf(tx[2]); a[3] = f2bf(tx[3]);
      }
      #pragma unroll
      for (int ht = 0; ht < 4; ++ht) {
        bf16x8 bfr = *reinterpret_cast<const bf16x8*>(
            &wdf_lds[((12 + q) * 64 + ht * 16 + p) * 8]);
        acc[ht] = __builtin_amdgcn_mfma_f32_16x16x32_bf16(a, bfr, acc[ht], 0, 0, 0);
      }
    }

    // ---- gate: acc[j][h] *= atomh[b,j,h]  (D: row j=16n+4q+r, col h=16ht+p) ----
    #pragma unroll
    for (int ht = 0; ht < 4; ++ht) {
      #pragma unroll
      for (int r = 0; r < 4; ++r) acc[ht][r] *= ah[n & 1][ht][r];
    }

    // ---- write gated (bf16, XOR-swizzled [16][64]) over this slab's chunk-0 words ----
    ushort* gb = reinterpret_cast<ushort*>(lb);
    #pragma unroll
    for (int r = 0; r < 4; ++r) {
      int rr = 4 * q + r;
      int sw = (rr & 7) << 3;
      #pragma unroll
      for (int ht = 0; ht < 4; ++ht)
        gb[rr * 64 + ((ht * 16 + p) ^ sw)] = (ushort)f2bf(acc[ht][r]);
    }
    asm volatile("" ::: "memory");         // keep phase-2 reads below the writes

    // ---- phase 2: pre[j,f] = gated[j,:].W_fc[:,f], K=64 ----
    f32x4 acc2[4];
    #pragma unroll
    for (int ft = 0; ft < 4; ++ft) acc2[ft] = (f32x4){0.f, 0.f, 0.f, 0.f};
    #pragma unroll
    for (int ks = 0; ks < 2; ++ks) {
      int h0 = (ks * 32 + q * 8) ^ ((p & 7) << 3);
      bf16x8 a2 = *reinterpret_cast<const bf16x8*>(&gb[p * 64 + h0]);
      #pragma unroll
      for (int ft = 0; ft < 4; ++ft) {
        bf16x8 bfr = *reinterpret_cast<const bf16x8*>(
            &wfc_lds[((ks * 4 + q) * 64 + ft * 16 + p) * 8]);
        acc2[ft] = __builtin_amdgcn_mfma_f32_16x16x32_bf16(a2, bfr, acc2[ft], 0, 0, 0);
      }
    }

    // ---- mask, tanh, accumulate (zero VMEM) ----
    #pragma unroll
    for (int r = 0; r < 4; ++r) {
      #pragma unroll
      for (int ft = 0; ft < 4; ++ft) s[ft] += fast_tanh(acc2[ft][r] * mv[n & 1][r]);
    }
  }

  // ---- reduce over q in-wave; single plain store per wave (wave owns all j of bi) ----
  #pragma unroll
  for (int ft = 0; ft < 4; ++ft) {
    s[ft] += __shfl_xor(s[ft], 16, 64);
    s[ft] += __shfl_xor(s[ft], 32, 64);
  }
  if (q == 0) {
    #pragma unroll
    for (int ft = 0; ft < 4; ++ft) {
      int o = bi * NFd + ft * 16 + p;
      out[o] = s[ft] + AF[o];
    }
  }
}

extern "C" void kernel_launch(void* const* d_in, const int* in_sizes, int n_in,
                              void* d_out, int out_size, void* d_ws, size_t ws_size,
                              hipStream_t stream) {
  const float* AF   = (const float*)d_in[0];
  const float* DM   = (const float*)d_in[1];
  const float* MASK = (const float*)d_in[2];
  const float* Wcf  = (const float*)d_in[3];
  const float* Wdf  = (const float*)d_in[4];
  const float* Wfc  = (const float*)d_in[5];
  const float* bcf  = (const float*)d_in[6];
  const float* bdf  = (const float*)d_in[7];
  float* out = (float*)d_out;

  float*  atomhT = (float*)d_ws;                                  // 512 KB (transposed [b][h][j])
  ushort* wdfp   = (ushort*)((char*)d_ws + 524288);               // 16 KB (K padded to 128)
  ushort* wfcp   = (ushort*)((char*)d_ws + 524288 + 16384);       // 8 KB

  prep_kernel<<<560, 256, 0, stream>>>(AF, Wcf, bcf, Wdf, Wfc, atomhT, wdfp, wfcp);
  dtnn_main_kernel<<<512, 256, 0, stream>>>(AF, DM, MASK, bdf, atomhT, wdfp, wfcp, out);
}

// Round 11
// 33.950 us; speedup vs baseline: 1.2269x; 1.0018x over previous
//
#include <hip/hip_runtime.h>
#include <hip/hip_bf16.h>

#define Bsz 16
#define Nn  128
#define NFd 64
#define NDd 100
#define NHd 64

typedef __attribute__((ext_vector_type(8))) short bf16x8;
typedef __attribute__((ext_vector_type(4))) float f32x4;

__device__ __forceinline__ short f2bf(float f) {
  return (short)__builtin_bit_cast(ushort, __float2bfloat16(f));
}

__device__ __forceinline__ float fast_tanh(float x) {
  // tanh(x) = 1 - 2/(exp(2x)+1); exact at +/-inf, ~1ulp rcp error (<< bf16 noise)
  float e = __expf(2.0f * x);
  return 1.0f - 2.0f * __builtin_amdgcn_rcpf(e + 1.0f);
}

// async global->LDS DMA: LDS dest = uniform base + lane*size; global src per-lane
__device__ __forceinline__ void glds16(const float* g, float* l) {
  __builtin_amdgcn_global_load_lds(
      (const __attribute__((address_space(1))) void*)g,
      (__attribute__((address_space(3))) void*)l, 16, 0, 0);
}
__device__ __forceinline__ void glds4(const float* g, float* l) {
  __builtin_amdgcn_global_load_lds(
      (const __attribute__((address_space(1))) void*)g,
      (__attribute__((address_space(3))) void*)l, 4, 0, 0);
}

// ---------------- prep kernel ----------------
// blocks [0,512):   atomhT[b,h,j] = b_cf[h] + sum_f AF[b,j,f]*W_cf[f,h]  (transposed)
// blocks [512,544): pack W_df -> bf16 MFMA-B fragments, K zero-padded to 128
// blocks [544,560): pack W_fc -> bf16 MFMA-B fragments (K=64)
__global__ __launch_bounds__(256) void prep_kernel(
    const float* __restrict__ AF, const float* __restrict__ Wcf,
    const float* __restrict__ bcf, const float* __restrict__ Wdf,
    const float* __restrict__ Wfc, float* __restrict__ atomhT,
    ushort* __restrict__ wdfp, ushort* __restrict__ wfcp) {
  int t = threadIdx.x;
  int blk = blockIdx.x;
  if (blk < 512) {
    int row = blk * 4 + (t >> 6);        // b*N + j
    int h = t & 63;
    const float* af = AF + (size_t)row * NFd;
    float a0 = 0.f, a1 = 0.f, a2 = 0.f, a3 = 0.f;
    #pragma unroll 4
    for (int f = 0; f < NFd; f += 4) {
      a0 += af[f + 0] * Wcf[(f + 0) * NHd + h];
      a1 += af[f + 1] * Wcf[(f + 1) * NHd + h];
      a2 += af[f + 2] * Wcf[(f + 2) * NHd + h];
      a3 += af[f + 3] * Wcf[(f + 3) * NHd + h];
    }
    int b = row >> 7, j = row & 127;
    atomhT[((size_t)(b * NHd + h)) << 7 | j] = bcf[h] + ((a0 + a1) + (a2 + a3));
  } else if (blk < 544) {
    // wdfp[(grp*64 + col)*8 + e] = bf16(Wdf[k = grp*8+e][col]), 0 if k >= 100
    int idx = (blk - 512) * 256 + t;     // [0, 8192)
    int e = idx & 7;
    int col = (idx >> 3) & 63;
    int grp = idx >> 9;
    int k = grp * 8 + e;
    float v = (k < NDd) ? Wdf[k * NHd + col] : 0.f;
    wdfp[idx] = (ushort)f2bf(v);
  } else {
    int idx = (blk - 544) * 256 + t;     // [0, 4096)
    int e = idx & 7;
    int col = (idx >> 3) & 63;
    int grp = idx >> 9;
    int k = grp * 8 + e;
    wfcp[idx] = (ushort)f2bf(Wfc[k * NFd + col]);
  }
}

// ---------------- main kernel: 512 persistent blocks, wave w owns bi = 4*blk + w ----------------
// 8 tiles of 16 j-rows per wave, software-pipelined with EXACT vmcnt bookkeeping:
// per tile the ONLY VMEM is 7 GLDS + 4 gate + 1 mask = 12 ops (weights live in LDS,
// read via lgkmcnt; no atomics; out written once per wave). Steady state:
// ISSUE(n+1)[12] -> s_waitcnt vmcnt(12) (retires exactly tile n) -> COMPUTE(n) (LDS-only).
// Every wave keeps 12-24 loads in flight continuously -> smooth HBM stream.
__global__ __launch_bounds__(256, 2) void dtnn_main_kernel(
    const float* __restrict__ AF,
    const float* __restrict__ DM,
    const float* __restrict__ MASK,
    const float* __restrict__ bdf,
    const float* __restrict__ atomhT,
    const ushort* __restrict__ wdfp,
    const ushort* __restrict__ wfcp,
    float* __restrict__ out) {
  __shared__ float  stage[4 * 2 * 1600];   // 51.2 KB: wave w, parity par -> w*3200 + par*1600
  __shared__ ushort wdf_lds[8192];         // 16 KB  phase-1 B fragments
  __shared__ ushort wfc_lds[4096];         // 8 KB   phase-2 B fragments

  const int t    = threadIdx.x;
  const int w    = t >> 6;
  const int lane = t & 63;
  const int p    = t & 15;
  const int q    = (t >> 4) & 3;

  const int bi = blockIdx.x * 4 + w;       // this wave's output row (b*N + i)
  const int b  = bi >> 7;

  // ---- stage weights into LDS (6 GLDS per wave, round-robin), zero VGPR cost ----
  {
    const float* wsrc = (const float*)wdfp;           // 16 KB = 16 x 1KB ops
    float* wdst = reinterpret_cast<float*>(wdf_lds);
    #pragma unroll
    for (int m = 0; m < 4; ++m) {
      int k = w + 4 * m;
      glds16(wsrc + k * 256 + lane * 4, wdst + k * 256);
    }
    const float* fsrc = (const float*)wfcp;           // 8 KB = 8 x 1KB ops
    float* fdst = reinterpret_cast<float*>(wfc_lds);
    #pragma unroll
    for (int m = 0; m < 2; ++m) {
      int k = w + 4 * m;
      glds16(fsrc + k * 256 + lane * 4, fdst + k * 256);
    }
  }

  // bias fragments (tile-invariant) -> registers, before the barrier drain
  float bv[4];
  #pragma unroll
  for (int ht = 0; ht < 4; ++ht) bv[ht] = bdf[ht * 16 + p];

  const float* gD = DM + (size_t)bi * (Nn * NDd);
  f32x4 ah[2][4];                          // gate operands, double-buffered by tile parity
  f32x4 mv[2];
  const int r8 = lane >> 3, b8 = lane & 7;

  // ISSUE(n): exactly 12 VMEM ops (7 GLDS k-major swizzled + 4 gate + 1 mask)
  auto ISSUE = [&](int n) {
    const float* gsrc = gD + n * 1600;
    float* lb = &stage[w * 3200 + (n & 1) * 1600];
    #pragma unroll
    for (int c = 0; c < 3; ++c) {
      #pragma unroll
      for (int g = 0; g < 2; ++g) {
        int r = g * 8 + r8;
        glds16(gsrc + r * 100 + c * 32 + ((b8 ^ (r & 7)) << 2),
               lb + c * 512 + g * 256);
      }
    }
    glds4(gsrc + (lane >> 2) * 100 + 96 + (lane & 3), lb + 1536);
    const int jrow = n * 16;
    #pragma unroll
    for (int ht = 0; ht < 4; ++ht)
      ah[n & 1][ht] = *reinterpret_cast<const f32x4*>(
          atomhT + (((size_t)(b * NHd + ht * 16 + p)) << 7) + jrow + 4 * q);
    mv[n & 1] = *reinterpret_cast<const f32x4*>(MASK + (size_t)bi * Nn + jrow + 4 * q);
  };

  ISSUE(0);
  __syncthreads();                         // weights (and tile 0) resident; once per block

  float s[4] = {0.f, 0.f, 0.f, 0.f};

  #pragma unroll
  for (int n = 0; n < 8; ++n) {
    if (n < 7) {
      ISSUE(n + 1);
      asm volatile("s_waitcnt vmcnt(12)" ::: "memory");  // retires exactly tile n's 12 ops
    } else {
      asm volatile("s_waitcnt vmcnt(0)" ::: "memory");
    }
    __builtin_amdgcn_sched_barrier(0);

    float* lb = &stage[w * 3200 + (n & 1) * 1600];

    // ---- phase 1: dist_h[j,h] = dm[j,:].W_df[:,h] + b_df[h], K=100 ----
    f32x4 acc[4];
    #pragma unroll
    for (int ht = 0; ht < 4; ++ht) acc[ht] = (f32x4){bv[ht], bv[ht], bv[ht], bv[ht]};

    #pragma unroll
    for (int ks = 0; ks < 3; ++ks) {       // k = [0,96), conflict-free swizzled reads
      const float* cbase = lb + ks * 512 + p * 32;
      f32x4 x = *reinterpret_cast<const f32x4*>(cbase + (((2 * q)    ) ^ (p & 7)) * 4);
      f32x4 y = *reinterpret_cast<const f32x4*>(cbase + (((2 * q) + 1) ^ (p & 7)) * 4);
      bf16x8 a;
      a[0] = f2bf(x[0]); a[1] = f2bf(x[1]); a[2] = f2bf(x[2]); a[3] = f2bf(x[3]);
      a[4] = f2bf(y[0]); a[5] = f2bf(y[1]); a[6] = f2bf(y[2]); a[7] = f2bf(y[3]);
      #pragma unroll
      for (int ht = 0; ht < 4; ++ht) {
        bf16x8 bfr = *reinterpret_cast<const bf16x8*>(
            &wdf_lds[((ks * 4 + q) * 64 + ht * 16 + p) * 8]);
        acc[ht] = __builtin_amdgcn_mfma_f32_16x16x32_bf16(a, bfr, acc[ht], 0, 0, 0);
      }
    }
    {                                      // tail k = [96,100): only q==0 carries data
      bf16x8 a = (bf16x8){0, 0, 0, 0, 0, 0, 0, 0};
      if (q == 0) {
        f32x4 tx = *reinterpret_cast<const f32x4*>(lb + 1536 + 4 * p);
        a[0] = f2bf(tx[0]); a[1] = f2bf(tx[1]); a[2] = f2bf(tx[2]); a[3] = f2bf(tx[3]);
      }
      #pragma unroll
      for (int ht = 0; ht < 4; ++ht) {
        bf16x8 bfr = *reinterpret_cast<const bf16x8*>(
            &wdf_lds[((12 + q) * 64 + ht * 16 + p) * 8]);
        acc[ht] = __builtin_amdgcn_mfma_f32_16x16x32_bf16(a, bfr, acc[ht], 0, 0, 0);
      }
    }

    // ---- gate: acc[j][h] *= atomh[b,j,h]  (D: row j=16n+4q+r, col h=16ht+p) ----
    #pragma unroll
    for (int ht = 0; ht < 4; ++ht) {
      #pragma unroll
      for (int r = 0; r < 4; ++r) acc[ht][r] *= ah[n & 1][ht][r];
    }

    // ---- write gated (bf16, XOR-swizzled [16][64]) over this slab's chunk-0 words ----
    ushort* gb = reinterpret_cast<ushort*>(lb);
    #pragma unroll
    for (int r = 0; r < 4; ++r) {
      int rr = 4 * q + r;
      int sw = (rr & 7) << 3;
      #pragma unroll
      for (int ht = 0; ht < 4; ++ht)
        gb[rr * 64 + ((ht * 16 + p) ^ sw)] = (ushort)f2bf(acc[ht][r]);
    }
    asm volatile("" ::: "memory");         // keep phase-2 reads below the writes

    // ---- phase 2: pre[j,f] = gated[j,:].W_fc[:,f], K=64 ----
    f32x4 acc2[4];
    #pragma unroll
    for (int ft = 0; ft < 4; ++ft) acc2[ft] = (f32x4){0.f, 0.f, 0.f, 0.f};
    #pragma unroll
    for (int ks = 0; ks < 2; ++ks) {
      int h0 = (ks * 32 + q * 8) ^ ((p & 7) << 3);
      bf16x8 a2 = *reinterpret_cast<const bf16x8*>(&gb[p * 64 + h0]);
      #pragma unroll
      for (int ft = 0; ft < 4; ++ft) {
        bf16x8 bfr = *reinterpret_cast<const bf16x8*>(
            &wfc_lds[((ks * 4 + q) * 64 + ft * 16 + p) * 8]);
        acc2[ft] = __builtin_amdgcn_mfma_f32_16x16x32_bf16(a2, bfr, acc2[ft], 0, 0, 0);
      }
    }

    // ---- mask, tanh, accumulate (zero VMEM) ----
    #pragma unroll
    for (int r = 0; r < 4; ++r) {
      #pragma unroll
      for (int ft = 0; ft < 4; ++ft) s[ft] += fast_tanh(acc2[ft][r] * mv[n & 1][r]);
    }
  }

  // ---- reduce over q in-wave; single plain store per wave (wave owns all j of bi) ----
  #pragma unroll
  for (int ft = 0; ft < 4; ++ft) {
    s[ft] += __shfl_xor(s[ft], 16, 64);
    s[ft] += __shfl_xor(s[ft], 32, 64);
  }
  if (q == 0) {
    #pragma unroll
    for (int ft = 0; ft < 4; ++ft) {
      int o = bi * NFd + ft * 16 + p;
      out[o] = s[ft] + AF[o];
    }
  }
}

extern "C" void kernel_launch(void* const* d_in, const int* in_sizes, int n_in,
                              void* d_out, int out_size, void* d_ws, size_t ws_size,
                              hipStream_t stream) {
  const float* AF   = (const float*)d_in[0];
  const float* DM   = (const float*)d_in[1];
  const float* MASK = (const float*)d_in[2];
  const float* Wcf  = (const float*)d_in[3];
  const float* Wdf  = (const float*)d_in[4];
  const float* Wfc  = (const float*)d_in[5];
  const float* bcf  = (const float*)d_in[6];
  const float* bdf  = (const float*)d_in[7];
  float* out = (float*)d_out;

  float*  atomhT = (float*)d_ws;                                  // 512 KB (transposed [b][h][j])
  ushort* wdfp   = (ushort*)((char*)d_ws + 524288);               // 16 KB (K padded to 128)
  ushort* wfcp   = (ushort*)((char*)d_ws + 524288 + 16384);       // 8 KB

  prep_kernel<<<560, 256, 0, stream>>>(AF, Wcf, bcf, Wdf, Wfc, atomhT, wdfp, wfcp);
  dtnn_main_kernel<<<512, 256, 0, stream>>>(AF, DM, MASK, bdf, atomhT, wdfp, wfcp, out);
}